// Round 1
// baseline (894.164 us; speedup 1.0000x reference)
//
#include <hip/hip_runtime.h>
#include <math.h>

#define EPS      1e-7f
#define N_ROWS   8192
#define DIM_X    256
#define DIM_Z    64
#define KNN      5
#define NSPLIT   4
#define RB       32            // rows per block
#define JT       128           // j-tile width
#define KC       16            // K chunk
#define JS       (N_ROWS / NSPLIT)
#define AS_STRIDE (RB + 4)     // pad to keep float4 alignment (stride 36 dwords)

__device__ __forceinline__ bool lexlt(float d, int j, float d2, int j2) {
    return (d < d2) || (d == d2 && j < j2);
}

// ---------------------------------------------------------------- zero out
__global__ void zero_out_k(float* o) { o[0] = 0.0f; }

// ---------------------------------------------------------------- row sums of squares for X
__global__ __launch_bounds__(256) void rowsq_k(const float* __restrict__ X,
                                               float* __restrict__ sqX) {
    const int row  = blockIdx.x * 4 + (threadIdx.x >> 6);
    const int lane = threadIdx.x & 63;
    const float4 v = *(const float4*)&X[(size_t)row * DIM_X + lane * 4];
    float s = v.x * v.x + v.y * v.y + v.z * v.z + v.w * v.w;
    #pragma unroll
    for (int o = 32; o > 0; o >>= 1) s += __shfl_down(s, o);
    if (lane == 0) sqX[row] = s;
}

// ---------------------------------------------------------------- fused GEMM + top-5
// grid: (N_ROWS/RB, NSPLIT), block: 256 threads (16 rows-threads x ... -> tr in [0,8), tc in [0,32))
__global__ __launch_bounds__(256) void gemm_topk_k(const float* __restrict__ X,
                                                   const float* __restrict__ sqX,
                                                   float2* __restrict__ partials) {
    // LDS: GEMM staging (first 10.5 KB) unioned with the merge buffer (40 KB)
    __shared__ __align__(16) char smem[RB * 32 * KNN * sizeof(float2)]; // 40960 B
    float*  As = (float*)smem;                         // [KC][AS_STRIDE] = 16*36 floats = 2304 B
    float*  Bs = (float*)(smem + KC * AS_STRIDE * 4);  // [KC][JT] = 16*128 floats = 8192 B
    float2* mergebuf = (float2*)smem;                  // used after GEMM phase

    const int tid = threadIdx.x;
    const int tc  = tid & 31;       // col-thread
    const int tr  = tid >> 5;       // row-thread (0..7)
    const int ib  = blockIdx.x * RB;
    const int s   = blockIdx.y;
    const int jb0 = s * JS;

    // running top-5 per owned row (4 rows/thread), sorted ascending by (d2, j)
    float bd[4][KNN];
    int   bi[4][KNN];
    #pragma unroll
    for (int r = 0; r < 4; ++r)
        #pragma unroll
        for (int k = 0; k < KNN; ++k) { bd[r][k] = 3.0e38f; bi[r][k] = 0x7fffffff; }

    const float4 sqi4 = *(const float4*)&sqX[ib + 4 * tr];
    const float sqi[4] = {sqi4.x, sqi4.y, sqi4.z, sqi4.w};

    // staging thread mappings
    const int kA   = (tid & 7) * 2;   // 0..14, loads float2 along K
    const int rowA = tid >> 3;        // 0..31
    const int colB = tid >> 1;        // 0..127
    const int kB   = (tid & 1) * 8;   // 0 or 8, loads 2x float4 along K

    for (int jt = 0; jt < JS / JT; ++jt) {
        const int jb = jb0 + jt * JT;
        float acc[4][4];
        #pragma unroll
        for (int r = 0; r < 4; ++r)
            #pragma unroll
            for (int c = 0; c < 4; ++c) acc[r][c] = 0.0f;

        for (int kc = 0; kc < DIM_X / KC; ++kc) {
            __syncthreads();  // protect previous LDS readers before overwrite
            // stage A: 32 rows x 16 k
            const float2 av = *(const float2*)&X[(size_t)(ib + rowA) * DIM_X + kc * KC + kA];
            As[(kA + 0) * AS_STRIDE + rowA] = av.x;
            As[(kA + 1) * AS_STRIDE + rowA] = av.y;
            // stage B: 128 cols x 16 k (stored transposed: Bs[k][col])
            const float4 bv0 = *(const float4*)&X[(size_t)(jb + colB) * DIM_X + kc * KC + kB + 0];
            const float4 bv1 = *(const float4*)&X[(size_t)(jb + colB) * DIM_X + kc * KC + kB + 4];
            Bs[(kB + 0) * JT + colB] = bv0.x;
            Bs[(kB + 1) * JT + colB] = bv0.y;
            Bs[(kB + 2) * JT + colB] = bv0.z;
            Bs[(kB + 3) * JT + colB] = bv0.w;
            Bs[(kB + 4) * JT + colB] = bv1.x;
            Bs[(kB + 5) * JT + colB] = bv1.y;
            Bs[(kB + 6) * JT + colB] = bv1.z;
            Bs[(kB + 7) * JT + colB] = bv1.w;
            __syncthreads();
            #pragma unroll
            for (int kk = 0; kk < KC; ++kk) {
                const float4 a = *(const float4*)&As[kk * AS_STRIDE + 4 * tr];
                const float4 b = *(const float4*)&Bs[kk * JT + 4 * tc];
                const float av_[4] = {a.x, a.y, a.z, a.w};
                const float bv_[4] = {b.x, b.y, b.z, b.w};
                #pragma unroll
                for (int r = 0; r < 4; ++r)
                    #pragma unroll
                    for (int c = 0; c < 4; ++c)
                        acc[r][c] = fmaf(av_[r], bv_[c], acc[r][c]);
            }
        }

        // fold this j-tile's 16 candidates per thread into the running top-5
        const float4 sqj4 = *(const float4*)&sqX[jb + 4 * tc];
        const float sqj[4] = {sqj4.x, sqj4.y, sqj4.z, sqj4.w};
        #pragma unroll
        for (int c = 0; c < 4; ++c) {
            const int j = jb + 4 * tc + c;
            #pragma unroll
            for (int r = 0; r < 4; ++r) {
                const int i = ib + 4 * tr + r;
                if (j == i) continue;  // reference drops the self column
                const float d2 = sqi[r] + sqj[c] - 2.0f * acc[r][c];
                if (lexlt(d2, j, bd[r][KNN - 1], bi[r][KNN - 1])) {
                    float cd = d2; int cj = j;
                    #pragma unroll
                    for (int k = 0; k < KNN; ++k) {
                        if (lexlt(cd, cj, bd[r][k], bi[r][k])) {
                            const float td = bd[r][k]; bd[r][k] = cd; cd = td;
                            const int   tj = bi[r][k]; bi[r][k] = cj; cj = tj;
                        }
                    }
                }
            }
        }
    }

    // block-level merge across the 32 col-threads per row
    __syncthreads();  // all GEMM-phase LDS reads done; smem repurposed
    #pragma unroll
    for (int r = 0; r < 4; ++r) {
        const int row = 4 * tr + r;
        #pragma unroll
        for (int k = 0; k < KNN; ++k)
            mergebuf[(row * 32 + tc) * KNN + k] =
                make_float2(bd[r][k], __int_as_float(bi[r][k]));
    }
    __syncthreads();
    if (tid < RB) {
        const int row = tid;
        float od[KNN]; int oi[KNN];
        #pragma unroll
        for (int k = 0; k < KNN; ++k) { od[k] = 3.0e38f; oi[k] = 0x7fffffff; }
        const float2* cand = &mergebuf[row * 32 * KNN];
        for (int t = 0; t < 32 * KNN; ++t) {
            float cd = cand[t].x;
            int   cj = __float_as_int(cand[t].y);
            if (lexlt(cd, cj, od[KNN - 1], oi[KNN - 1])) {
                #pragma unroll
                for (int k = 0; k < KNN; ++k) {
                    if (lexlt(cd, cj, od[k], oi[k])) {
                        const float td = od[k]; od[k] = cd; cd = td;
                        const int   tj = oi[k]; oi[k] = cj; cj = tj;
                    }
                }
            }
        }
        #pragma unroll
        for (int k = 0; k < KNN; ++k)
            partials[(size_t)(ib + row) * (NSPLIT * KNN) + s * KNN + k] =
                make_float2(od[k], __int_as_float(oi[k]));
    }
}

// ---------------------------------------------------------------- final merge + LID + loss
__global__ __launch_bounds__(256) void finalize_k(const float2* __restrict__ partials,
                                                  const float* __restrict__ Z,
                                                  float* __restrict__ out) {
    const int i = blockIdx.x * 256 + threadIdx.x;  // 0..8191

    float od[KNN]; int oi[KNN];
    #pragma unroll
    for (int k = 0; k < KNN; ++k) { od[k] = 3.0e38f; oi[k] = 0x7fffffff; }
    #pragma unroll
    for (int t = 0; t < NSPLIT * KNN; ++t) {
        const float2 c = partials[(size_t)i * (NSPLIT * KNN) + t];
        float cd = c.x;
        int   cj = __float_as_int(c.y);
        if (lexlt(cd, cj, od[KNN - 1], oi[KNN - 1])) {
            #pragma unroll
            for (int k = 0; k < KNN; ++k) {
                if (lexlt(cd, cj, od[k], oi[k])) {
                    const float td = od[k]; od[k] = cd; cd = td;
                    const int   tj = oi[k]; oi[k] = cj; cj = tj;
                }
            }
        }
    }

    // lid_X (norm factor cancels: ratio (d_j+EPS)/(d_5+EPS))
    const float l4 = log10f(sqrtf(fmaxf(od[KNN - 1], 0.0f)) + EPS);
    float lx = 0.0f;
    #pragma unroll
    for (int k = 0; k < KNN; ++k)
        lx -= (log10f(sqrtf(fmaxf(od[k], 0.0f)) + EPS) - l4);

    // z-distances at the 5 X-neighbors (order = ascending X-distance)
    const float4* zi = (const float4*)(Z + (size_t)i * DIM_Z);
    float4 ziv[DIM_Z / 4];
    float sqzi = 0.0f;
    #pragma unroll
    for (int d = 0; d < DIM_Z / 4; ++d) {
        ziv[d] = zi[d];
        sqzi += ziv[d].x * ziv[d].x + ziv[d].y * ziv[d].y +
                ziv[d].z * ziv[d].z + ziv[d].w * ziv[d].w;
    }
    float e[KNN];
    #pragma unroll
    for (int k = 0; k < KNN; ++k) {
        const float4* zj = (const float4*)(Z + (size_t)oi[k] * DIM_Z);
        float dot = 0.0f, sq = 0.0f;
        #pragma unroll
        for (int d = 0; d < DIM_Z / 4; ++d) {
            const float4 b = zj[d];
            dot += ziv[d].x * b.x + ziv[d].y * b.y + ziv[d].z * b.z + ziv[d].w * b.w;
            sq  += b.x * b.x + b.y * b.y + b.z * b.z + b.w * b.w;
        }
        const float d2z = sqzi + sq - 2.0f * dot;
        e[k] = sqrtf(fmaxf(d2z, 0.0f)) + EPS;
    }
    const float l4z = log10f(e[KNN - 1]);
    float lz = 0.0f;
    #pragma unroll
    for (int k = 0; k < KNN; ++k) lz -= (log10f(e[k]) - l4z);

    const float diff = lx - lz;
    float val = diff * diff * (1.0f / ((float)N_ROWS * KNN * 10.0f));

    // block reduction -> one atomic per block
    #pragma unroll
    for (int o = 32; o > 0; o >>= 1) val += __shfl_down(val, o);
    __shared__ float wsum[4];
    if ((threadIdx.x & 63) == 0) wsum[threadIdx.x >> 6] = val;
    __syncthreads();
    if (threadIdx.x == 0)
        atomicAdd(out, wsum[0] + wsum[1] + wsum[2] + wsum[3]);
}

// ---------------------------------------------------------------- launch
extern "C" void kernel_launch(void* const* d_in, const int* in_sizes, int n_in,
                              void* d_out, int out_size, void* d_ws, size_t ws_size,
                              hipStream_t stream) {
    const float* X = (const float*)d_in[0];
    const float* Z = (const float*)d_in[1];
    float* out = (float*)d_out;

    float*  sqX      = (float*)d_ws;                                  // 8192 floats
    float2* partials = (float2*)((char*)d_ws + N_ROWS * sizeof(float)); // 8192*20 float2

    zero_out_k<<<1, 1, 0, stream>>>(out);
    rowsq_k<<<N_ROWS / 4, 256, 0, stream>>>(X, sqX);
    gemm_topk_k<<<dim3(N_ROWS / RB, NSPLIT), 256, 0, stream>>>(X, sqX, partials);
    finalize_k<<<N_ROWS / 256, 256, 0, stream>>>(partials, Z, out);
}

// Round 2
// 460.630 us; speedup vs baseline: 1.9412x; 1.9412x over previous
//
#include <hip/hip_runtime.h>
#include <math.h>

#define EPS     1e-7f
#define NR      8192
#define DX      256
#define DZ      64
#define KNN     5
#define KEEP    6              // per-split kept candidates (margin 1)
#define NCAND   8              // exact-recompute count in finalize
#define NSPLIT  4
#define JS      (NR / NSPLIT)  // 2048
#define JT      64             // j-cols per chunk
#define RBLK    64             // i-rows per block
#define RW      16             // i-rows per wave
#define INV2048 (1.0f / 2048.0f)

typedef _Float16 f16x8 __attribute__((ext_vector_type(8)));
typedef _Float16 f16x4 __attribute__((ext_vector_type(4)));
typedef float    f32x4 __attribute__((ext_vector_type(4)));

__device__ __forceinline__ bool lexlt(float d, int j, float d2, int j2) {
    return (d < d2) || (d == d2 && j < j2);
}

// ---------------------------------------------------------------- zero out
__global__ void zero_out_k(float* o) { o[0] = 0.0f; }

// ------------------------------------------------- split X into f16 hi/lo + row sq-sums
// lo is pre-scaled by 2048 so it stays in f16 normal range (no denorm-flush risk).
__global__ __launch_bounds__(256) void split_k(const float* __restrict__ X,
                                               _Float16* __restrict__ Xh,
                                               _Float16* __restrict__ Xl,
                                               float* __restrict__ sqX) {
    const int row  = blockIdx.x * 4 + (threadIdx.x >> 6);
    const int lane = threadIdx.x & 63;
    const float4 v = *(const float4*)&X[(size_t)row * DX + lane * 4];
    float s = v.x * v.x + v.y * v.y + v.z * v.z + v.w * v.w;
    f16x4 h, l;
    h[0] = (_Float16)v.x; l[0] = (_Float16)((v.x - (float)h[0]) * 2048.0f);
    h[1] = (_Float16)v.y; l[1] = (_Float16)((v.y - (float)h[1]) * 2048.0f);
    h[2] = (_Float16)v.z; l[2] = (_Float16)((v.z - (float)h[2]) * 2048.0f);
    h[3] = (_Float16)v.w; l[3] = (_Float16)((v.w - (float)h[3]) * 2048.0f);
    *(f16x4*)&Xh[(size_t)row * DX + lane * 4] = h;
    *(f16x4*)&Xl[(size_t)row * DX + lane * 4] = l;
    #pragma unroll
    for (int o = 32; o > 0; o >>= 1) s += __shfl_down(s, o);
    if (lane == 0) sqX[row] = s;
}

// ------------------------------------------------- MFMA split-f16 GEMM + fused top-k
// block: 256 thr = 4 waves; wave owns 16 i-rows (A frags in registers);
// B (64 j-rows x 256 k, hi+lo) staged in 64 KB LDS per chunk, XOR-swizzled 16B chunks.
__global__ __launch_bounds__(256, 2) void mfma_topk_k(const _Float16* __restrict__ Xh,
                                                      const _Float16* __restrict__ Xl,
                                                      const float* __restrict__ sqX,
                                                      float2* __restrict__ partials) {
    __shared__ __align__(16) char smem[65536];
    f16x8* BhV = (f16x8*)smem;              // 2048 x 16B chunks
    f16x8* BlV = (f16x8*)(smem + 32768);
    float2* mergebuf = (float2*)smem;       // repurposed after GEMM phase

    const int tid  = threadIdx.x;
    const int w    = tid >> 6;
    const int lane = tid & 63;
    const int n    = lane & 15;
    const int quad = lane >> 4;
    const int ib   = blockIdx.x * RBLK;
    const int jb0  = blockIdx.y * JS;
    const int iw   = ib + w * RW;

    // A fragments: 8 k-steps x (hi, lo), held for the whole kernel (64 VGPR)
    f16x8 Ah[8], Al[8];
    #pragma unroll
    for (int ks = 0; ks < 8; ++ks) {
        Ah[ks] = *(const f16x8*)(Xh + (size_t)(iw + n) * DX + ks * 32 + quad * 8);
        Al[ks] = *(const f16x8*)(Xl + (size_t)(iw + n) * DX + ks * 32 + quad * 8);
    }
    const float4 sqi4 = *(const float4*)&sqX[iw + quad * 4];
    const float sqi[4] = {sqi4.x, sqi4.y, sqi4.z, sqi4.w};
    const int ibase = iw + quad * 4;   // lane's rows: ibase + r  (C layout: row = quad*4+reg)

    float bd[4][KNN]; int bi[4][KNN];
    #pragma unroll
    for (int r = 0; r < 4; ++r)
        #pragma unroll
        for (int k = 0; k < KNN; ++k) { bd[r][k] = 3.0e38f; bi[r][k] = 0x7fffffff; }

    // staging mapping: thread -> (row sj, chunk base sc); 64B-contiguous per 4-thread group
    const int sj  = tid >> 2;
    const int sc  = tid & 3;
    const int swb = sj & 7;
    const int x7  = n & 7;

    for (int jc = 0; jc < JS / JT; ++jc) {
        const int jb = jb0 + jc * JT;
        __syncthreads();  // previous chunk's LDS readers done
        const f16x8* rh = (const f16x8*)(Xh + (size_t)(jb + sj) * DX);
        const f16x8* rl = (const f16x8*)(Xl + (size_t)(jb + sj) * DX);
        #pragma unroll
        for (int u = 0; u < 8; ++u) {
            const int c   = u * 4 + sc;
            const int dst = sj * 32 + (c ^ swb);
            BhV[dst] = rh[c];
            BlV[dst] = rl[c];
        }
        __syncthreads();

        f32x4 acc1[4], acc2[4];
        #pragma unroll
        for (int s = 0; s < 4; ++s)
            #pragma unroll
            for (int r = 0; r < 4; ++r) { acc1[s][r] = 0.0f; acc2[s][r] = 0.0f; }

        #pragma unroll
        for (int ks = 0; ks < 8; ++ks) {
            const int c = ks * 4 + quad;
            #pragma unroll
            for (int s = 0; s < 4; ++s) {
                const int a16 = s * 512 + n * 32 + (c ^ x7);
                const f16x8 bh = BhV[a16];
                const f16x8 bl = BlV[a16];
                acc1[s] = __builtin_amdgcn_mfma_f32_16x16x32_f16(Ah[ks], bh, acc1[s], 0, 0, 0);
                acc2[s] = __builtin_amdgcn_mfma_f32_16x16x32_f16(Ah[ks], bl, acc2[s], 0, 0, 0);
                acc2[s] = __builtin_amdgcn_mfma_f32_16x16x32_f16(Al[ks], bh, acc2[s], 0, 0, 0);
            }
        }

        // fold 16 candidates/lane into running top-5 (rows quad*4+r, col s*16+n)
        #pragma unroll
        for (int s = 0; s < 4; ++s) {
            const int j = jb + s * 16 + n;
            const float sqj = sqX[j];
            #pragma unroll
            for (int r = 0; r < 4; ++r) {
                if (j == ibase + r) continue;  // self
                const float d2 = sqi[r] + sqj - 2.0f * (acc1[s][r] + acc2[s][r] * INV2048);
                if (lexlt(d2, j, bd[r][KNN - 1], bi[r][KNN - 1])) {
                    float cd = d2; int cj = j;
                    #pragma unroll
                    for (int k = 0; k < KNN; ++k) {
                        if (lexlt(cd, cj, bd[r][k], bi[r][k])) {
                            const float td = bd[r][k]; bd[r][k] = cd; cd = td;
                            const int   tj = bi[r][k]; bi[r][k] = cj; cj = tj;
                        }
                    }
                }
            }
        }
    }

    // block merge: per row, 16 lanes x 5 candidates -> top-KEEP
    __syncthreads();
    #pragma unroll
    for (int r = 0; r < 4; ++r) {
        const int rl_ = w * RW + quad * 4 + r;
        const int base = rl_ * 16 * KNN + n * KNN;
        #pragma unroll
        for (int k = 0; k < KNN; ++k)
            mergebuf[base + k] = make_float2(bd[r][k], __int_as_float(bi[r][k]));
    }
    __syncthreads();
    if (tid < RBLK) {
        float od[KEEP]; int oi[KEEP];
        #pragma unroll
        for (int k = 0; k < KEEP; ++k) { od[k] = 3.0e38f; oi[k] = 0x7fffffff; }
        const float2* cand = &mergebuf[tid * 16 * KNN];
        for (int t = 0; t < 16 * KNN; ++t) {
            float cd = cand[t].x;
            int   cj = __float_as_int(cand[t].y);
            if (lexlt(cd, cj, od[KEEP - 1], oi[KEEP - 1])) {
                #pragma unroll
                for (int k = 0; k < KEEP; ++k) {
                    if (lexlt(cd, cj, od[k], oi[k])) {
                        const float td = od[k]; od[k] = cd; cd = td;
                        const int   tj = oi[k]; oi[k] = cj; cj = tj;
                    }
                }
            }
        }
        #pragma unroll
        for (int k = 0; k < KEEP; ++k)
            partials[(size_t)(ib + tid) * (NSPLIT * KEEP) + blockIdx.y * KEEP + k] =
                make_float2(od[k], __int_as_float(oi[k]));
    }
}

// ------------------------------------------------- merge splits, exact fp32 re-rank, LID, loss
__global__ __launch_bounds__(256) void finalize_k(const float2* __restrict__ parts,
                                                  const float* __restrict__ X,
                                                  const float* __restrict__ Z,
                                                  const float* __restrict__ sqX,
                                                  float* __restrict__ out) {
    const int i = blockIdx.x * 256 + threadIdx.x;

    // approx top-NCAND across the 4 splits (24 candidates)
    float ad[NCAND]; int ai[NCAND];
    #pragma unroll
    for (int k = 0; k < NCAND; ++k) { ad[k] = 3.0e38f; ai[k] = 0x7fffffff; }
    #pragma unroll
    for (int t = 0; t < NSPLIT * KEEP; ++t) {
        const float2 c = parts[(size_t)i * (NSPLIT * KEEP) + t];
        float cd = c.x;
        int   cj = __float_as_int(c.y);
        if (lexlt(cd, cj, ad[NCAND - 1], ai[NCAND - 1])) {
            #pragma unroll
            for (int k = 0; k < NCAND; ++k) {
                if (lexlt(cd, cj, ad[k], ai[k])) {
                    const float td = ad[k]; ad[k] = cd; cd = td;
                    const int   tj = ai[k]; ai[k] = cj; cj = tj;
                }
            }
        }
    }

    // exact fp32 d^2 for the NCAND candidates
    const float4* xi = (const float4*)(X + (size_t)i * DX);
    const float sqi = sqX[i];
    float ed[NCAND];
    #pragma unroll
    for (int t = 0; t < NCAND; ++t) {
        const int j = ai[t];
        const float4* xj = (const float4*)(X + (size_t)j * DX);
        float dot = 0.0f;
        for (int d = 0; d < DX / 4; ++d) {
            const float4 a = xi[d], b = xj[d];
            dot = fmaf(a.x, b.x, dot); dot = fmaf(a.y, b.y, dot);
            dot = fmaf(a.z, b.z, dot); dot = fmaf(a.w, b.w, dot);
        }
        ed[t] = sqi + sqX[j] - 2.0f * dot;
    }

    // exact top-5 (lex on (d2, j))
    float od[KNN]; int oi[KNN];
    #pragma unroll
    for (int k = 0; k < KNN; ++k) { od[k] = 3.0e38f; oi[k] = 0x7fffffff; }
    #pragma unroll
    for (int t = 0; t < NCAND; ++t) {
        float cd = ed[t]; int cj = ai[t];
        if (lexlt(cd, cj, od[KNN - 1], oi[KNN - 1])) {
            #pragma unroll
            for (int k = 0; k < KNN; ++k) {
                if (lexlt(cd, cj, od[k], oi[k])) {
                    const float td = od[k]; od[k] = cd; cd = td;
                    const int   tj = oi[k]; oi[k] = cj; cj = tj;
                }
            }
        }
    }

    // lid_X (norm cancels: ratio (d_k+EPS)/(d_5+EPS))
    const float l4 = log10f(sqrtf(fmaxf(od[KNN - 1], 0.0f)) + EPS);
    float lx = 0.0f;
    #pragma unroll
    for (int k = 0; k < KNN; ++k)
        lx -= (log10f(sqrtf(fmaxf(od[k], 0.0f)) + EPS) - l4);

    // z-distances at the 5 X-neighbors
    const float4* zi = (const float4*)(Z + (size_t)i * DZ);
    float4 ziv[DZ / 4];
    float sqzi = 0.0f;
    #pragma unroll
    for (int d = 0; d < DZ / 4; ++d) {
        ziv[d] = zi[d];
        sqzi += ziv[d].x * ziv[d].x + ziv[d].y * ziv[d].y +
                ziv[d].z * ziv[d].z + ziv[d].w * ziv[d].w;
    }
    float e[KNN];
    #pragma unroll
    for (int k = 0; k < KNN; ++k) {
        const float4* zj = (const float4*)(Z + (size_t)oi[k] * DZ);
        float dot = 0.0f, sq = 0.0f;
        #pragma unroll
        for (int d = 0; d < DZ / 4; ++d) {
            const float4 b = zj[d];
            dot += ziv[d].x * b.x + ziv[d].y * b.y + ziv[d].z * b.z + ziv[d].w * b.w;
            sq  += b.x * b.x + b.y * b.y + b.z * b.z + b.w * b.w;
        }
        const float d2z = sqzi + sq - 2.0f * dot;
        e[k] = sqrtf(fmaxf(d2z, 0.0f)) + EPS;
    }
    const float l4z = log10f(e[KNN - 1]);
    float lz = 0.0f;
    #pragma unroll
    for (int k = 0; k < KNN; ++k) lz -= (log10f(e[k]) - l4z);

    const float diff = lx - lz;
    float val = diff * diff * (1.0f / ((float)NR * KNN * 10.0f));

    #pragma unroll
    for (int o = 32; o > 0; o >>= 1) val += __shfl_down(val, o);
    __shared__ float wsum[4];
    if ((threadIdx.x & 63) == 0) wsum[threadIdx.x >> 6] = val;
    __syncthreads();
    if (threadIdx.x == 0)
        atomicAdd(out, wsum[0] + wsum[1] + wsum[2] + wsum[3]);
}

// ---------------------------------------------------------------- launch
extern "C" void kernel_launch(void* const* d_in, const int* in_sizes, int n_in,
                              void* d_out, int out_size, void* d_ws, size_t ws_size,
                              hipStream_t stream) {
    const float* X = (const float*)d_in[0];
    const float* Z = (const float*)d_in[1];
    float* out = (float*)d_out;

    char* ws = (char*)d_ws;
    float*     sqX      = (float*)ws;                              // 32 KB
    float2*    partials = (float2*)(ws + 32768);                   // 8192*24*8 = 1.5 MB
    _Float16*  Xh       = (_Float16*)(ws + 32768 + 1572864);       // 4 MB
    _Float16*  Xl       = (_Float16*)(ws + 32768 + 1572864 + 4194304); // 4 MB

    zero_out_k<<<1, 1, 0, stream>>>(out);
    split_k<<<NR / 4, 256, 0, stream>>>(X, Xh, Xl, sqX);
    mfma_topk_k<<<dim3(NR / RBLK, NSPLIT), 256, 0, stream>>>(Xh, Xl, sqX, partials);
    finalize_k<<<NR / 256, 256, 0, stream>>>(partials, X, Z, sqX, out);
}

// Round 3
// 198.464 us; speedup vs baseline: 4.5054x; 2.3210x over previous
//
#include <hip/hip_runtime.h>
#include <math.h>
#include <stdint.h>

#define EPS     1e-7f
#define NR      8192
#define DX      256
#define DZ      64
#define KNN     5
#define KEEP    8               // per-split kept candidates (packed u32)
#define NCAND   12              // exact-recompute pool in finalize
#define NSPLIT  4
#define JS      (NR / NSPLIT)   // 2048
#define JT      64              // j-cols staged per chunk
#define NCHUNK  (JS / JT)       // 32
#define RBLK    64              // i-rows per block

typedef _Float16 f16x8 __attribute__((ext_vector_type(8)));
typedef _Float16 f16x4 __attribute__((ext_vector_type(4)));
typedef float    f32x4 __attribute__((ext_vector_type(4)));

// ---------------------------------------------------------------- zero out
__global__ void zero_out_k(float* o) { o[0] = 0.0f; }

// ------------------------------------------------- X -> f16 (hi only) + row sq-sums
__global__ __launch_bounds__(256) void split_k(const float* __restrict__ X,
                                               _Float16* __restrict__ Xh,
                                               float* __restrict__ sqX) {
    const int row  = blockIdx.x * 4 + (threadIdx.x >> 6);
    const int lane = threadIdx.x & 63;
    const float4 v = *(const float4*)&X[(size_t)row * DX + lane * 4];
    float s = v.x * v.x + v.y * v.y + v.z * v.z + v.w * v.w;
    f16x4 h;
    h[0] = (_Float16)v.x; h[1] = (_Float16)v.y;
    h[2] = (_Float16)v.z; h[3] = (_Float16)v.w;
    *(f16x4*)&Xh[(size_t)row * DX + lane * 4] = h;
    #pragma unroll
    for (int o = 32; o > 0; o >>= 1) s += __shfl_down(s, o);
    if (lane == 0) sqX[row] = s;
}

// ------------------------------------------------- f16 MFMA GEMM + fused packed top-5
// 4 waves/block. Wave w: rows half h=w>>1 (32 rows, A in regs), j-subchunk pair sp=w&1.
// B staged via global_load_lds (16B), source-side XOR swizzle; candidates packed
// (d2_bits & ~0x1FFF)|j so top-k is a u32 min chain (exact re-rank later fixes quantization).
__global__ __launch_bounds__(256, 2) void mfma_topk_k(const _Float16* __restrict__ Xh,
                                                      const float* __restrict__ sqX,
                                                      uint32_t* __restrict__ partials) {
    __shared__ __align__(16) uint8_t smem[40960];   // staging 32768 B | merge 40960 B
    f16x8*    BhV = (f16x8*)smem;                   // 2048 slots x 16 B
    uint32_t* mb  = (uint32_t*)smem;                // merge phase: 64 rows x 32 x KNN

    const int tid  = threadIdx.x;
    const int w    = tid >> 6;
    const int lane = tid & 63;
    const int n    = lane & 15;
    const int quad = lane >> 4;
    const int x7   = n & 7;
    const int h    = w >> 1;
    const int sp   = w & 1;
    const int ib   = blockIdx.x * RBLK;
    const int jb0  = blockIdx.y * JS;
    const int rowbase = ib + h * 32;

    // A fragments: 2 rowgroups x 8 k-steps, held whole kernel (64 VGPR)
    f16x8 Ah[2][8];
    #pragma unroll
    for (int g = 0; g < 2; ++g)
        #pragma unroll
        for (int ks = 0; ks < 8; ++ks)
            Ah[g][ks] = *(const f16x8*)(Xh + (size_t)(rowbase + g * 16 + n) * DX + ks * 32 + quad * 8);

    float sqi[2][4];
    #pragma unroll
    for (int g = 0; g < 2; ++g) {
        const float4 t = *(const float4*)&sqX[rowbase + g * 16 + quad * 4];
        sqi[g][0] = t.x; sqi[g][1] = t.y; sqi[g][2] = t.z; sqi[g][3] = t.w;
    }

    uint32_t best[8][KNN];
    #pragma unroll
    for (int q = 0; q < 8; ++q)
        #pragma unroll
        for (int k = 0; k < KNN; ++k) best[q][k] = 0xFFFFFFFFu;

    // staging source map: slot q = w*512 + u*64 + lane holds row sj=q>>5, chunk c=(q&31)^(sj&7)
    int srcoff[8];
    #pragma unroll
    for (int u = 0; u < 8; ++u) {
        const int q  = w * 512 + u * 64 + lane;
        const int sj = q >> 5;
        const int c  = (q & 31) ^ (sj & 7);
        srcoff[u] = sj * DX + c * 8;
    }

    for (int jc = 0; jc < NCHUNK; ++jc) {
        const int jb = jb0 + jc * JT;
        __syncthreads();  // previous chunk's readers done
        #pragma unroll
        for (int u = 0; u < 8; ++u) {
            const _Float16* src = Xh + (size_t)jb * DX + srcoff[u];
            uint8_t* dst = smem + (size_t)(w * 512 + u * 64) * 16;  // wave-uniform; HW adds lane*16
            __builtin_amdgcn_global_load_lds((const __attribute__((address_space(1))) uint32_t*)src,
                                             (__attribute__((address_space(3))) uint32_t*)dst,
                                             16, 0, 0);
        }
        __syncthreads();  // barrier drains vmcnt -> staging visible

        f32x4 acc[2][2];  // [si][g]
        #pragma unroll
        for (int si = 0; si < 2; ++si)
            #pragma unroll
            for (int g = 0; g < 2; ++g)
                #pragma unroll
                for (int r = 0; r < 4; ++r) acc[si][g][r] = 0.0f;

        #pragma unroll
        for (int ks = 0; ks < 8; ++ks) {
            #pragma unroll
            for (int si = 0; si < 2; ++si) {
                const int s   = sp * 2 + si;
                const int idx = (s * 16 + n) * 32 + ((ks * 4 + quad) ^ x7);
                const f16x8 b = BhV[idx];
                acc[si][0] = __builtin_amdgcn_mfma_f32_16x16x32_f16(Ah[0][ks], b, acc[si][0], 0, 0, 0);
                acc[si][1] = __builtin_amdgcn_mfma_f32_16x16x32_f16(Ah[1][ks], b, acc[si][1], 0, 0, 0);
            }
        }

        // fold 16 candidates/lane (C layout: col=n, row=quad*4+r)
        #pragma unroll
        for (int si = 0; si < 2; ++si) {
            const int j = jb + (sp * 2 + si) * 16 + n;
            const float sqj = sqX[j];
            #pragma unroll
            for (int g = 0; g < 2; ++g) {
                #pragma unroll
                for (int r = 0; r < 4; ++r) {
                    const int i = rowbase + g * 16 + quad * 4 + r;
                    if (j == i) continue;  // self (reference drops diagonal)
                    const float d2 = (sqi[g][r] + sqj) - 2.0f * acc[si][g][r];
                    const uint32_t cand = (__float_as_uint(d2) & 0xFFFFE000u) | (uint32_t)j;
                    const int q = g * 4 + r;
                    if (cand < best[q][KNN - 1]) {
                        uint32_t ck = cand;
                        #pragma unroll
                        for (int k = 0; k < KNN; ++k) {
                            const uint32_t bk = best[q][k];
                            const uint32_t mn = ck < bk ? ck : bk;
                            const uint32_t mx = ck < bk ? bk : ck;
                            best[q][k] = mn; ck = mx;
                        }
                    }
                }
            }
        }
    }

    // block merge: per row, 32 lanes x 5 packed -> top-KEEP
    __syncthreads();
    #pragma unroll
    for (int g = 0; g < 2; ++g)
        #pragma unroll
        for (int r = 0; r < 4; ++r) {
            const int rloc = h * 32 + g * 16 + quad * 4 + r;
            const int widx = sp * 16 + n;
            uint32_t* dst = &mb[(rloc * 32 + widx) * KNN];
            #pragma unroll
            for (int k = 0; k < KNN; ++k) dst[k] = best[g * 4 + r][k];
        }
    __syncthreads();
    if (tid < RBLK) {
        uint32_t ob[KEEP];
        #pragma unroll
        for (int k = 0; k < KEEP; ++k) ob[k] = 0xFFFFFFFFu;
        const uint32_t* cd = &mb[tid * 32 * KNN];
        for (int t = 0; t < 32 * KNN; ++t) {
            uint32_t ck = cd[t];
            if (ck < ob[KEEP - 1]) {
                #pragma unroll
                for (int k = 0; k < KEEP; ++k) {
                    const uint32_t bk = ob[k];
                    const uint32_t mn = ck < bk ? ck : bk;
                    const uint32_t mx = ck < bk ? bk : ck;
                    ob[k] = mn; ck = mx;
                }
            }
        }
        #pragma unroll
        for (int k = 0; k < KEEP; ++k)
            partials[(size_t)(ib + tid) * (NSPLIT * KEEP) + blockIdx.y * KEEP + k] = ob[k];
    }
}

// ------------------------------------------------- one wave per row: approx-rank prefilter,
// exact fp32 re-rank (4 lanes/candidate), lid, loss
__global__ __launch_bounds__(1024) void finalize_k(const uint32_t* __restrict__ parts,
                                                   const float* __restrict__ X,
                                                   const float* __restrict__ Z,
                                                   const float* __restrict__ sqX,
                                                   float* __restrict__ out) {
    __shared__ uint32_t jl[16][NCAND];
    __shared__ float wsum[16];
    const int wv   = threadIdx.x >> 6;
    const int lane = threadIdx.x & 63;
    const int i    = blockIdx.x * 16 + wv;

    // rank the 32 packed candidates (splits disjoint -> keys distinct)
    uint32_t packed = 0xFFFFFFFFu;
    if (lane < 32) packed = parts[(size_t)i * (NSPLIT * KEEP) + lane];
    int rank = 0;
    #pragma unroll
    for (int m = 0; m < 32; ++m) {
        const uint32_t v = __shfl(packed, m);
        rank += (v < packed) || (v == packed && m < lane);
    }
    if (lane < 32 && rank < NCAND) jl[wv][rank] = packed & 0x1FFFu;
    __syncthreads();

    // exact fp32 d2 for NCAND candidates: candidate c = lane>>2, quarter = lane&3
    const int c = lane >> 2, qtr = lane & 3;
    unsigned long long key = 0xFFFFFFFFFFFFFFFFull;
    if (c < NCAND) {
        const int j = (int)jl[wv][c];
        const float4* xi = (const float4*)(X + (size_t)i * DX) + qtr * 16;
        const float4* xj = (const float4*)(X + (size_t)j * DX) + qtr * 16;
        float a0 = 0.f, a1 = 0.f, a2 = 0.f, a3 = 0.f;
        #pragma unroll
        for (int t = 0; t < 16; t += 4) {
            const float4 u0 = xi[t],     v0 = xj[t];
            const float4 u1 = xi[t + 1], v1 = xj[t + 1];
            const float4 u2 = xi[t + 2], v2 = xj[t + 2];
            const float4 u3 = xi[t + 3], v3 = xj[t + 3];
            a0 = fmaf(u0.x, v0.x, fmaf(u0.y, v0.y, fmaf(u0.z, v0.z, fmaf(u0.w, v0.w, a0))));
            a1 = fmaf(u1.x, v1.x, fmaf(u1.y, v1.y, fmaf(u1.z, v1.z, fmaf(u1.w, v1.w, a1))));
            a2 = fmaf(u2.x, v2.x, fmaf(u2.y, v2.y, fmaf(u2.z, v2.z, fmaf(u2.w, v2.w, a2))));
            a3 = fmaf(u3.x, v3.x, fmaf(u3.y, v3.y, fmaf(u3.z, v3.z, fmaf(u3.w, v3.w, a3))));
        }
        float dot = (a0 + a1) + (a2 + a3);
        dot += __shfl_xor(dot, 1);
        dot += __shfl_xor(dot, 2);
        const float d2 = (sqX[i] + sqX[j]) - 2.0f * dot;
        key = ((unsigned long long)__float_as_uint(d2) << 32) | (unsigned)j;
    }

    // exact top-5 by (d2, j): 5x u64 butterfly-min; duplicate lanes collapse by value
    float od[KNN]; int oi[KNN];
    #pragma unroll
    for (int k = 0; k < KNN; ++k) {
        unsigned long long m = key;
        #pragma unroll
        for (int off = 1; off < 64; off <<= 1) {
            const unsigned long long o = __shfl_xor(m, off);
            m = o < m ? o : m;
        }
        od[k] = __uint_as_float((uint32_t)(m >> 32));
        oi[k] = (int)(m & 0x1FFFull);
        if (key == m) key = 0xFFFFFFFFFFFFFFFFull;
    }

    // lid_X (quantile norm cancels in the log-ratio)
    const float l4 = log10f(sqrtf(fmaxf(od[KNN - 1], 0.0f)) + EPS);
    float lx = 0.0f;
    #pragma unroll
    for (int k = 0; k < KNN; ++k)
        lx -= (log10f(sqrtf(fmaxf(od[k], 0.0f)) + EPS) - l4);

    // z-distances at the 5 X-neighbors: lane k < 5 computes sum((zi-zj)^2)
    float lk = 0.0f;
    if (lane < KNN) {
        const int j = oi[lane];
        const float4* zi = (const float4*)(Z + (size_t)i * DZ);
        const float4* zj = (const float4*)(Z + (size_t)j * DZ);
        float a0 = 0.f, a1 = 0.f, a2 = 0.f, a3 = 0.f;
        #pragma unroll
        for (int t = 0; t < 16; t += 4) {
            const float4 u0 = zi[t],     v0 = zj[t];
            const float4 u1 = zi[t + 1], v1 = zj[t + 1];
            const float4 u2 = zi[t + 2], v2 = zj[t + 2];
            const float4 u3 = zi[t + 3], v3 = zj[t + 3];
            float4 d0, d1, d2_, d3;
            d0.x = u0.x - v0.x; d0.y = u0.y - v0.y; d0.z = u0.z - v0.z; d0.w = u0.w - v0.w;
            d1.x = u1.x - v1.x; d1.y = u1.y - v1.y; d1.z = u1.z - v1.z; d1.w = u1.w - v1.w;
            d2_.x = u2.x - v2.x; d2_.y = u2.y - v2.y; d2_.z = u2.z - v2.z; d2_.w = u2.w - v2.w;
            d3.x = u3.x - v3.x; d3.y = u3.y - v3.y; d3.z = u3.z - v3.z; d3.w = u3.w - v3.w;
            a0 = fmaf(d0.x, d0.x, fmaf(d0.y, d0.y, fmaf(d0.z, d0.z, fmaf(d0.w, d0.w, a0))));
            a1 = fmaf(d1.x, d1.x, fmaf(d1.y, d1.y, fmaf(d1.z, d1.z, fmaf(d1.w, d1.w, a1))));
            a2 = fmaf(d2_.x, d2_.x, fmaf(d2_.y, d2_.y, fmaf(d2_.z, d2_.z, fmaf(d2_.w, d2_.w, a2))));
            a3 = fmaf(d3.x, d3.x, fmaf(d3.y, d3.y, fmaf(d3.z, d3.z, fmaf(d3.w, d3.w, a3))));
        }
        const float d2z = (a0 + a1) + (a2 + a3);
        lk = log10f(sqrtf(fmaxf(d2z, 0.0f)) + EPS);
    }
    const float l4z = __shfl(lk, KNN - 1);
    float slk = 0.0f;
    #pragma unroll
    for (int m = 0; m < KNN; ++m) slk += __shfl(lk, m);

    if (lane == 0) {
        const float lz   = -(slk - (float)KNN * l4z);
        const float diff = lx - lz;
        wsum[wv] = diff * diff * (1.0f / ((float)NR * KNN * 10.0f));
    }
    __syncthreads();
    if (threadIdx.x == 0) {
        float s = 0.0f;
        #pragma unroll
        for (int t = 0; t < 16; ++t) s += wsum[t];
        atomicAdd(out, s);
    }
}

// ---------------------------------------------------------------- launch
extern "C" void kernel_launch(void* const* d_in, const int* in_sizes, int n_in,
                              void* d_out, int out_size, void* d_ws, size_t ws_size,
                              hipStream_t stream) {
    const float* X = (const float*)d_in[0];
    const float* Z = (const float*)d_in[1];
    float* out = (float*)d_out;

    char* ws = (char*)d_ws;
    float*     sqX      = (float*)ws;                         // 32 KB
    uint32_t*  partials = (uint32_t*)(ws + 32768);            // 8192*32*4 = 1 MB
    _Float16*  Xh       = (_Float16*)(ws + 32768 + 1048576);  // 4 MB

    zero_out_k<<<1, 1, 0, stream>>>(out);
    split_k<<<NR / 4, 256, 0, stream>>>(X, Xh, sqX);
    mfma_topk_k<<<dim3(NR / RBLK, NSPLIT), 256, 0, stream>>>(Xh, sqX, partials);
    finalize_k<<<NR / 16, 1024, 0, stream>>>(partials, X, Z, sqX, out);
}